// Round 23
// baseline (168.349 us; speedup 1.0000x reference)
//
#include <hip/hip_runtime.h>
#include <float.h>
#include <math.h>

#define BB 4
#define TT 2048
#define CC 1024
#define HH 16
#define HD 64
#define C3 3072

typedef __bf16 bf16;
typedef __bf16 bf16x8 __attribute__((ext_vector_type(8)));
typedef __bf16 bf16x4 __attribute__((ext_vector_type(4)));
typedef float f32x4 __attribute__((ext_vector_type(4)));
typedef float f32x16 __attribute__((ext_vector_type(16)));
typedef unsigned int uint32x4 __attribute__((ext_vector_type(4)));

// 0.125 * log2(e): folds the 1/sqrt(hd) scale and the exp->exp2 base change
// into Q, so softmax runs in the log2 domain (v_exp_f32 is native exp2).
#define QSCALE 0.18033688f

__device__ __forceinline__ void gload16(const void* g, void* l) {
    __builtin_amdgcn_global_load_lds(
        (const __attribute__((address_space(1))) void*)g,
        (__attribute__((address_space(3))) void*)l, 16, 0, 0);
}

// ---------------- fused prep: cvt x->bf16 | transW wa | transW wp | table
//                  | cvt emb->bf16 (saves 16 MB of rope_rms traffic)
// One dispatch, block-range partitioned (branch is block-uniform).
__global__ __launch_bounds__(256) void prep_k(const float* __restrict__ x,
                                              bf16* __restrict__ xb,
                                              const float* __restrict__ wa,
                                              bf16* __restrict__ waT,
                                              const float* __restrict__ wp,
                                              bf16* __restrict__ wpT,
                                              float* __restrict__ tab,
                                              const float* __restrict__ emb,
                                              bf16* __restrict__ embB) {
    const int blk = (int)blockIdx.x;
    const int tid = threadIdx.x;
    __shared__ bf16 tile[64][72];

    if (blk < 4096) {                       // ---- cvt x: 4096*256 = n8 exactly
        int i = blk * 256 + tid;
        const float4* p = (const float4*)(x + (size_t)i * 8);
        float4 a = p[0], b = p[1];
        bf16x8 o;
        o[0] = (bf16)a.x; o[1] = (bf16)a.y; o[2] = (bf16)a.z; o[3] = (bf16)a.w;
        o[4] = (bf16)b.x; o[5] = (bf16)b.y; o[6] = (bf16)b.z; o[7] = (bf16)b.w;
        *(bf16x8*)(xb + (size_t)i * 8) = o;
        return;
    }
    if (blk < 5120) {                       // ---- transW (wa: 768, wp: 256)
        const float* in;
        bf16* out;
        int K = 1024, N, bx, by;
        if (blk < 4864) {
            int r = blk - 4096;
            in = wa; out = waT; N = 3072;
            bx = r % 48; by = r / 48;
        } else {
            int r = blk - 4864;
            in = wp; out = wpT; N = 1024;
            bx = r & 15; by = r >> 4;
        }
        int n0 = bx * 64, k0 = by * 64;
        int r = tid >> 2, c4 = (tid & 3) * 16;
        const float4* src = (const float4*)(in + (size_t)(k0 + r) * N + n0 + c4);
        #pragma unroll
        for (int j = 0; j < 4; ++j) {
            float4 v = src[j];
            tile[r][c4 + 4 * j + 0] = (bf16)v.x; tile[r][c4 + 4 * j + 1] = (bf16)v.y;
            tile[r][c4 + 4 * j + 2] = (bf16)v.z; tile[r][c4 + 4 * j + 3] = (bf16)v.w;
        }
        __syncthreads();
        bf16x8 o0, o1;
        #pragma unroll
        for (int j = 0; j < 8; ++j) o0[j] = tile[c4 + j][r];
        #pragma unroll
        for (int j = 0; j < 8; ++j) o1[j] = tile[c4 + 8 + j][r];
        *(bf16x8*)(out + (size_t)(n0 + r) * K + k0 + c4) = o0;
        *(bf16x8*)(out + (size_t)(n0 + r) * K + k0 + c4 + 8) = o1;
        return;
    }
    if (blk < 5376) {                       // ---- rope table: 256*256 = TT*32
        int idx = (blk - 5120) * 256 + tid;
        int t = idx >> 5;
        int j = idx & 31;
        float freq = powf(10000.0f, -((float)(2 * j)) / 64.0f);
        float ang = (float)t * freq;
        tab[idx] = cosf(ang);
        tab[TT * 32 + idx] = sinf(ang);
        return;
    }
    {                                       // ---- cvt emb: 1024 blocks
        int i = (blk - 5376) * 256 + tid;   // 1024*256*8 = 2048*1024
        const float4* p = (const float4*)(emb + (size_t)i * 8);
        float4 a = p[0], b = p[1];
        bf16x8 o;
        o[0] = (bf16)a.x; o[1] = (bf16)a.y; o[2] = (bf16)a.z; o[3] = (bf16)a.w;
        o[4] = (bf16)b.x; o[5] = (bf16)b.y; o[6] = (bf16)b.z; o[7] = (bf16)b.w;
        *(bf16x8*)(embB + (size_t)i * 8) = o;
    }
}

// ---------------------- qkv GEMM: 256x192 tile, BK=64, 8 waves (2M x 4N,
// per-wave 128x48). Counted-vmcnt pipeline via operand split: A 3-buffered
// (prefetch distance 2), B 2-buffered (distance 1). Per iter issue B(kt+1)
// THEN A(kt+2); publish with vmcnt(4) — A(kt+2)'s 4 wave-loads stay in
// flight ACROSS the barrier (T4). LDS 144 KiB. Grid 512 = 2 balanced rounds.
__global__ __launch_bounds__(512, 1) void gemm256_k(const bf16* __restrict__ A,
                                                    const bf16* __restrict__ BT,
                                                    bf16* __restrict__ Qh,
                                                    bf16* __restrict__ Kh,
                                                    bf16* __restrict__ Vh,
                                                    int M, int N, int K) {
    extern __shared__ bf16 smem[];   // A: 3 x 16384 | B(+49152): 2 x 12288
    const int tid = threadIdx.x;
    const int w = tid >> 6, lane = tid & 63;
    const int wm = w >> 2, wn = w & 3;          // per-wave 128 x 48
    const int nwg = (int)gridDim.x;             // 512
    const int cpx = nwg >> 3;
    const int flat = (int)blockIdx.x;
    const int wg = (flat & 7) * cpx + (flat >> 3);
    const int gx = N / 192;                     // 16
    const int n0 = (wg % gx) * 192;
    const int m0 = (wg / gx) * 256;

    const int srow = lane >> 3;
    const int schunk = (lane & 7) ^ srow;
    const int xorL = (lane & 7) << 3;
    const int KT = K >> 6;                      // 16

    f32x4 acc[8][3];
    #pragma unroll
    for (int i = 0; i < 8; ++i)
        #pragma unroll
        for (int j = 0; j < 3; ++j) acc[i][j] = {0.f, 0.f, 0.f, 0.f};

    auto stageA = [&](int kt) {                 // 4 wave-loads
        bf16* Abuf = smem + (kt % 3) * 16384;
        const int k0 = kt * 64;
        #pragma unroll
        for (int ri = 0; ri < 4; ++ri) {
            int row = ri * 64 + w * 8;
            gload16(A + (size_t)(m0 + row + srow) * K + k0 + schunk * 8,
                    Abuf + row * 64);
        }
    };
    auto stageB = [&](int kt) {                 // 3 wave-loads
        bf16* Bbuf = smem + 49152 + (kt & 1) * 12288;
        const int k0 = kt * 64;
        #pragma unroll
        for (int ri = 0; ri < 3; ++ri) {
            int row = ri * 64 + w * 8;
            gload16(BT + (size_t)(n0 + row + srow) * K + k0 + schunk * 8,
                    Bbuf + row * 64);
        }
    };

    // prologue: A(0), B(0), A(1) -> vmcnt(4) keeps A(1) in flight
    stageA(0);
    stageB(0);
    stageA(1);
    asm volatile("s_waitcnt vmcnt(4)" ::: "memory");
    __builtin_amdgcn_s_barrier();
    __builtin_amdgcn_sched_barrier(0);

    for (int kt = 0; kt < KT; ++kt) {
        if (kt + 1 < KT) stageB(kt + 1);   // issue B first (retired this barrier)
        if (kt + 2 < KT) stageA(kt + 2);   // A rides across the barrier
        const bf16* Al = smem + (kt % 3) * 16384;
        const bf16* Bl = smem + 49152 + (kt & 1) * 12288;
        #pragma unroll
        for (int kh = 0; kh < 2; ++kh) {
            const int off = (kh * 32 + (lane >> 4) * 8) ^ xorL;
            bf16x8 aF[8], bF[3];
            #pragma unroll
            for (int i = 0; i < 8; ++i)
                aF[i] = *(const bf16x8*)&Al[(wm * 128 + i * 16 + (lane & 15)) * 64 + off];
            #pragma unroll
            for (int j = 0; j < 3; ++j)
                bF[j] = *(const bf16x8*)&Bl[(wn * 48 + j * 16 + (lane & 15)) * 64 + off];
            __builtin_amdgcn_s_setprio(1);
            #pragma unroll
            for (int i = 0; i < 8; ++i)
                #pragma unroll
                for (int j = 0; j < 3; ++j)
                    acc[i][j] = __builtin_amdgcn_mfma_f32_16x16x32_bf16(
                        aF[i], bF[j], acc[i][j], 0, 0, 0);
            __builtin_amdgcn_s_setprio(0);
        }
        if (kt + 1 < KT) {
            if (kt + 2 < KT) {
                asm volatile("s_waitcnt vmcnt(4)" ::: "memory");
            } else {
                asm volatile("s_waitcnt vmcnt(0)" ::: "memory");
            }
            __builtin_amdgcn_s_barrier();
            __builtin_amdgcn_sched_barrier(0);
        }
    }

    // scatter epilogue: per 16-col group (192-wide tiles straddle Q/K/V
    // boundaries; 1024 is 16-aligned so each group maps to one region+head)
    const int ncb = n0 + wn * 48;
    #pragma unroll
    for (int j = 0; j < 3; ++j) {
        const int ncbj = ncb + j * 16;
        const int region = ncbj >> 10;
        const int hj = (ncbj & 1023) >> 6;
        const int cj = (ncbj & 63) + (lane & 15);
        bf16* dst = (region == 0) ? Qh : ((region == 1) ? Kh : Vh);
        #pragma unroll
        for (int i = 0; i < 8; ++i)
            #pragma unroll
            for (int r = 0; r < 4; ++r) {
                int m = m0 + wm * 128 + i * 16 + 4 * (lane >> 4) + r;
                int b = m >> 11, t = m & (TT - 1);
                dst[((size_t)(b * HH + hj) * TT + t) * HD + cj] = (bf16)acc[i][j][r];
            }
    }
}

// ------------------------------------------------------- proj GEMM (BT)
// 128x128 tile, 4 waves; issue-early double-buffer (64 KiB LDS -> 2
// blocks/CU, grid 512 = one full co-resident round). XCD region map:
// 8 regions of 8 m-tiles x all 8 n-tiles, n-fast (B set L2-resident).
__global__ __launch_bounds__(256) void gemm_bt_k(const bf16* __restrict__ A,
                                                 const bf16* __restrict__ BT,
                                                 float* __restrict__ C,
                                                 int M, int N, int K) {
    extern __shared__ bf16 psm[];   // [2][A 128*64 | B 128*64] = 64 KiB
    const int tid = threadIdx.x;
    const int w = tid >> 6, lane = tid & 63;
    const int flat = (int)blockIdx.x;           // 0..511 (64m x 8n)
    const int xcd = flat & 7;
    const int local = flat >> 3;                // 0..63
    const int lr = local >> 3, lc = local & 7;  // n-fast
    const int m0 = (xcd * 8 + lr) * 128;
    const int n0 = lc * 128;
    const int wrow = (w >> 1) * 64, wcol = (w & 1) * 64;
    const int srow = lane >> 3;
    const int schunk = (lane & 7) ^ srow;
    const int xorL = (lane & 7) << 3;
    const int KT = K >> 6;                      // 16

    const f32x4 fz = {0.f, 0.f, 0.f, 0.f};
    f32x4 acc[4][4];
    #pragma unroll
    for (int i = 0; i < 4; ++i)
        #pragma unroll
        for (int j = 0; j < 4; ++j) acc[i][j] = fz;

    // stage one K-tile: A 128 rows + B 128 rows = 256 rows, 8 rounds x 32
    auto stage = [&](int kt, bf16* buf) {
        const int k0 = kt * 64;
        #pragma unroll
        for (int ri = 0; ri < 8; ++ri) {
            int row = ri * 32 + w * 8;
            if (row < 128) {
                gload16(A + (size_t)(m0 + row + srow) * K + k0 + schunk * 8,
                        buf + row * 64);
            } else {
                int rb = row - 128;
                gload16(BT + (size_t)(n0 + rb + srow) * K + k0 + schunk * 8,
                        buf + 8192 + rb * 64);
            }
        }
    };

    stage(0, psm);
    __syncthreads();

    for (int kt = 0; kt < KT; ++kt) {
        const int buf = kt & 1;
        if (kt + 1 < KT) stage(kt + 1, psm + (buf ^ 1) * 16384);  // issue-early
        const bf16* Al = psm + buf * 16384;
        const bf16* Bl = Al + 8192;
        #pragma unroll
        for (int kh = 0; kh < 2; ++kh) {
            const int off = (kh * 32 + (lane >> 4) * 8) ^ xorL;
            bf16x8 aF[4], bF[4];
            #pragma unroll
            for (int i = 0; i < 4; ++i) {
                aF[i] = *(const bf16x8*)&Al[(wrow + i * 16 + (lane & 15)) * 64 + off];
                bF[i] = *(const bf16x8*)&Bl[(wcol + i * 16 + (lane & 15)) * 64 + off];
            }
            __builtin_amdgcn_s_setprio(1);
            #pragma unroll
            for (int i = 0; i < 4; ++i)
                #pragma unroll
                for (int j = 0; j < 4; ++j)
                    acc[i][j] = __builtin_amdgcn_mfma_f32_16x16x32_bf16(
                        aF[i], bF[j], acc[i][j], 0, 0, 0);
            __builtin_amdgcn_s_setprio(0);
        }
        __syncthreads();   // publish: drains stage(kt+1), guards buf reuse
    }

    #pragma unroll
    for (int i = 0; i < 4; ++i)
        #pragma unroll
        for (int r = 0; r < 4; ++r) {
            size_t rowm = (size_t)(m0 + wrow + i * 16 + 4 * (lane >> 4) + r);
            #pragma unroll
            for (int j = 0; j < 4; ++j)
                C[rowm * N + n0 + wcol + j * 16 + (lane & 15)] = acc[i][j][r];
        }
}

// --------------- RoPE + RMS on Qh/Kh (in place); V+emb -> transposed Vt.
// emb read as bf16 (pre-converted in prep_k; halves the emb stream).
__global__ __launch_bounds__(256) void rope_rms_k(bf16* __restrict__ Qh,
                                                  bf16* __restrict__ Kh,
                                                  const bf16* __restrict__ Vh,
                                                  bf16* __restrict__ Vt,
                                                  const bf16* __restrict__ embB,
                                                  const float* __restrict__ tab) {
    __shared__ bf16 tile[64][72];
    const int t0 = blockIdx.x * 64;
    const int bh = blockIdx.y;
    const int h = bh & (HH - 1);
    const int w = threadIdx.x >> 6, lane = threadIdx.x & 63;
    const int j = lane & 31;
    #pragma unroll 4
    for (int i = 0; i < 16; ++i) {
        const int tl = w * 16 + i;
        const int t = t0 + tl;
        const size_t base = ((size_t)bh * TT + t) * HD + lane;
        const float cs = tab[t * 32 + j];
        const float sn = tab[TT * 32 + t * 32 + j];
        float q = (float)Qh[base], k = (float)Kh[base], v = (float)Vh[base];
        float qp = __shfl_xor(q, 32, 64), kp = __shfl_xor(k, 32, 64);
        float rq = (lane < 32) ? q * cs - qp * sn : q * cs + qp * sn;
        float rk = (lane < 32) ? k * cs - kp * sn : k * cs + kp * sn;
        float sq = rq * rq, sk = rk * rk;
        #pragma unroll
        for (int off = 1; off < 64; off <<= 1) {
            sq += __shfl_xor(sq, off, 64);
            sk += __shfl_xor(sk, off, 64);
        }
        rq *= rsqrtf(sq * (1.0f / 64.0f) + 1.1920929e-07f);
        rk *= rsqrtf(sk * (1.0f / 64.0f) + 1.1920929e-07f);
        Qh[base] = (bf16)(rq * QSCALE);
        Kh[base] = (bf16)rk;
        tile[tl][lane] = (bf16)(v + (float)embB[(size_t)t * CC + h * HD + lane]);
    }
    __syncthreads();
    const int tt = threadIdx.x;
    const int r = tt >> 2, c4 = (tt & 3) * 16;
    bf16x8 o0, o1;
    #pragma unroll
    for (int jj = 0; jj < 8; ++jj) o0[jj] = tile[c4 + jj][r];
    #pragma unroll
    for (int jj = 0; jj < 8; ++jj) o1[jj] = tile[c4 + 8 + jj][r];
    bf16* out = Vt + (size_t)bh * HD * TT;
    *(bf16x8*)(out + (size_t)r * TT + t0 + c4) = o0;
    *(bf16x8*)(out + (size_t)r * TT + t0 + c4 + 8) = o1;
}

// ------------------------------------------------ MFMA flash attn (causal)
// 8 waves x 32 q-rows = 256 q rows/block, grid flat=512 blocks (2/CU).
// KVBLK=128, counted-vmcnt operand split: K 3-buffered (distance 2),
// V 2-buffered (distance 1). Per iter issue V(kt+1) THEN K(kt+2); publish
// with vmcnt(2) so K(kt+2) rides across the barrier. LDS 80 KiB.
// Swapped QK^T (S^T = K*Q^T, 32x32x16) -> in-register log2-domain softmax
// with defer-max; PV swapped (Y^T = V^T * P^T).
__global__ __launch_bounds__(512) void attn_k(const bf16* __restrict__ Qh,
                                              const bf16* __restrict__ Kh,
                                              const bf16* __restrict__ Vt,
                                              bf16* __restrict__ Y) {
    extern __shared__ bf16 asmem[];   // K: 3 x 8192 | V(+24576): 2 x 8192
    const int flat = (int)blockIdx.y * 8 + (int)blockIdx.x;   // 0..511
    const int slot = flat >> 3;
    const int bh = (flat & 7) * 8 + (slot & 7);   // fixes XCD per bh
    const int u = slot >> 3;                      // 0..7
    const int qb = (u < 4) ? (7 - u) : (u - 4);   // balanced CU pairs
    const int b = bh >> 4, h = bh & 15;
    const int tid = threadIdx.x, w = tid >> 6, lane = tid & 63;
    const int hi = lane >> 5, q31 = lane & 31;
    const int wq0 = qb * 256 + w * 32;
    const int qg = wq0 + q31;
    const int xr = q31 & 7;

    const bf16* Kbase = Kh + (size_t)bh * TT * HD;
    const bf16* Vbase = Vt + (size_t)bh * HD * TT;

    // Q B-operand fragments: lane holds Q[qg][ds*16 + hi*8 + 0..7]
    bf16x8 qF[4];
    {
        const bf16* qp = Qh + (size_t)bh * TT * HD + (size_t)qg * HD + hi * 8;
        #pragma unroll
        for (int ds = 0; ds < 4; ++ds) qF[ds] = *(const bf16x8*)(qp + ds * 16);
    }

    f32x16 accY[2];
    #pragma unroll
    for (int i = 0; i < 16; ++i) { accY[0][i] = 0.f; accY[1][i] = 0.f; }
    float mR = -INFINITY, lR = 0.f;

    const int srow = lane >> 3;                 // K staging: row-in-8
    const int schunk = (lane & 7) ^ srow;       // K pre-swizzled chunk
    const int vsr = lane >> 4;                  // V staging: row-in-4
    const int ktN = 2 * qb + 2;                 // 128-k tiles (>= 2)

    auto stageK = [&](int kt) {                 // 2 wave-loads
        bf16* dst = asmem + (kt % 3) * 8192;
        const int kc0 = kt * 128;
        #pragma unroll
        for (int jj = 0; jj < 2; ++jj) {
            int lr = w * 16 + jj * 8;
            gload16(Kbase + (size_t)(kc0 + lr + srow) * HD + schunk * 8,
                    dst + lr * 64);
        }
    };
    auto stageV = [&](int kt) {                 // 2 wave-loads
        bf16* dst = asmem + 24576 + (kt & 1) * 8192;
        const int kc0 = kt * 128;
        #pragma unroll
        for (int jj = 0; jj < 2; ++jj) {
            int vr = w * 8 + jj * 4;
            int vrow = vr + vsr;
            gload16(Vbase + (size_t)vrow * TT + kc0 + (((lane & 15) ^ (vrow & 7)) * 8),
                    dst + vr * 128);
        }
    };

    // prologue: K(0), V(0), K(1) -> vmcnt(2) keeps K(1) in flight (ktN>=2)
    stageK(0);
    stageV(0);
    stageK(1);
    asm volatile("s_waitcnt vmcnt(2)" ::: "memory");
    __builtin_amdgcn_s_barrier();
    __builtin_amdgcn_sched_barrier(0);

    for (int kt = 0; kt < ktN; ++kt) {
        if (kt + 1 < ktN) stageV(kt + 1);   // issue V first (retired this barrier)
        if (kt + 2 < ktN) stageK(kt + 2);   // K rides across the barrier
        const bf16* KL = asmem + (kt % 3) * 8192;
        const bf16* VL = asmem + 24576 + (kt & 1) * 8192;
        #pragma unroll
        for (int s = 0; s < 2; ++s) {
            if (kt * 128 + s * 64 > wq0 + 31) break;   // beyond causal frontier
            // ---- S^T = K @ Q^T : rows k (32 per frag), cols q ----
            f32x16 sa[2];
            #pragma unroll
            for (int i = 0; i < 16; ++i) { sa[0][i] = 0.f; sa[1][i] = 0.f; }
            __builtin_amdgcn_s_setprio(1);
            #pragma unroll
            for (int ds = 0; ds < 4; ++ds) {
                int cc = ds * 2 + hi;
                bf16x8 k0 = *(const bf16x8*)&KL[(s * 64 + q31) * 64 + ((cc ^ xr) * 8)];
                bf16x8 k1 = *(const bf16x8*)&KL[(s * 64 + 32 + q31) * 64 + ((cc ^ xr) * 8)];
                sa[0] = __builtin_amdgcn_mfma_f32_32x32x16_bf16(k0, qF[ds], sa[0], 0, 0, 0);
                sa[1] = __builtin_amdgcn_mfma_f32_32x32x16_bf16(k1, qF[ds], sa[1], 0, 0, 0);
            }
            __builtin_amdgcn_s_setprio(0);
            // ---- causal mask (only near-diagonal sub-tiles) ----
            if (kt * 128 + s * 64 + 63 > wq0) {
                #pragma unroll
                for (int kb = 0; kb < 2; ++kb)
                    #pragma unroll
                    for (int r = 0; r < 16; ++r) {
                        int k = kt * 128 + s * 64 + kb * 32 + (r & 3) + 8 * (r >> 2) + 4 * hi;
                        if (k > qg) sa[kb][r] = -1e30f;
                    }
            }
            // ---- in-register online softmax (log2 domain, defer-max) ----
            float mx = -1e30f;
            #pragma unroll
            for (int r = 0; r < 16; ++r)
                mx = fmaxf(fmaxf(sa[0][r], sa[1][r]), mx);
            mx = fmaxf(mx, __shfl_xor(mx, 32, 64));
            if (!__all(mx - mR <= 12.0f)) {   // scores bounded by 11.54
                float mnew = fmaxf(mR, mx);
                float alpha = __builtin_amdgcn_exp2f(mR - mnew);
                #pragma unroll
                for (int i = 0; i < 16; ++i) { accY[0][i] *= alpha; accY[1][i] *= alpha; }
                lR *= alpha;
                mR = mnew;
            }
            float sum0 = 0.f, sum1 = 0.f;
            #pragma unroll
            for (int r = 0; r < 16; ++r) {
                float p0 = __builtin_amdgcn_exp2f(sa[0][r] - mR);
                float p1 = __builtin_amdgcn_exp2f(sa[1][r] - mR);
                sa[0][r] = p0; sa[1][r] = p1;
                sum0 += p0; sum1 += p1;
            }
            float sum = sum0 + sum1;
            sum += __shfl_xor(sum, 32, 64);
            lR += sum;
            // ---- pack P to bf16 words, exchange halves, build B-frags ----
            unsigned int wds[2][8];
            #pragma unroll
            for (int kb = 0; kb < 2; ++kb)
                #pragma unroll
                for (int jj = 0; jj < 8; ++jj) {
                    bf16x8 tmp;   // only low 2 used
                    tmp[0] = (bf16)sa[kb][2 * jj];
                    tmp[1] = (bf16)sa[kb][2 * jj + 1];
                    wds[kb][jj] = *(unsigned int*)&tmp;
                }
            bf16x8 pF[4];
            #pragma unroll
            for (int ks = 0; ks < 4; ++ks) {
                const int kb = ks >> 1, ss = ks & 1;
                unsigned int w0 = wds[kb][4 * ss + 0], w1 = wds[kb][4 * ss + 1];
                unsigned int w2 = wds[kb][4 * ss + 2], w3 = wds[kb][4 * ss + 3];
                unsigned int t0 = hi ? w0 : w2, t1 = hi ? w1 : w3;
                unsigned int r0 = (unsigned int)__shfl_xor((int)t0, 32, 64);
                unsigned int r1 = (unsigned int)__shfl_xor((int)t1, 32, 64);
                uint32x4 fw;
                fw[0] = hi ? r0 : w0; fw[1] = hi ? r1 : w1;
                fw[2] = hi ? w2 : r0; fw[3] = hi ? w3 : r1;
                pF[ks] = *(bf16x8*)&fw;
            }
            // ---- Y^T += V^T @ P^T  (V row = d, 128-col k; chunk-XOR swz) ----
            __builtin_amdgcn_s_setprio(1);
            #pragma unroll
            for (int cd = 0; cd < 2; ++cd) {
                const int rowD = cd * 32 + q31;
                #pragma unroll
                for (int ks = 0; ks < 4; ++ks) {
                    int cc = s * 8 + ks * 2 + hi;    // chunk within 128 cols
                    bf16x8 vA = *(const bf16x8*)&VL[rowD * 128 + ((cc ^ xr) * 8)];
                    accY[cd] = __builtin_amdgcn_mfma_f32_32x32x16_bf16(
                        vA, pF[ks], accY[cd], 0, 0, 0);
                }
            }
            __builtin_amdgcn_s_setprio(0);
        }
        if (kt + 1 < ktN) {
            if (kt + 2 < ktN) {
                asm volatile("s_waitcnt vmcnt(2)" ::: "memory");
            } else {
                asm volatile("s_waitcnt vmcnt(0)" ::: "memory");
            }
            __builtin_amdgcn_s_barrier();
            __builtin_amdgcn_sched_barrier(0);
        }
    }

    // epilogue: Y[qg][h*64 + d] = accY/l ; d = cd*32 + 8g + 4hi + 0..3
    float inv = 1.0f / lR;
    bf16* yp = Y + ((size_t)(b * TT + qg)) * CC + h * HD;
    #pragma unroll
    for (int cd = 0; cd < 2; ++cd)
        #pragma unroll
        for (int g = 0; g < 4; ++g) {
            int d0 = cd * 32 + 8 * g + 4 * hi;
            bf16x4 o;
            o[0] = (bf16)(accY[cd][4 * g + 0] * inv);
            o[1] = (bf16)(accY[cd][4 * g + 1] * inv);
            o[2] = (bf16)(accY[cd][4 * g + 2] * inv);
            o[3] = (bf16)(accY[cd][4 * g + 3] * inv);
            *(bf16x4*)(yp + d0) = o;
        }
}

extern "C" void kernel_launch(void* const* d_in, const int* in_sizes, int n_in,
                              void* d_out, int out_size, void* d_ws, size_t ws_size,
                              hipStream_t stream) {
    const float* x         = (const float*)d_in[0];
    const float* w_attn    = (const float*)d_in[1];
    const float* w_proj    = (const float*)d_in[2];
    const float* val_embed = (const float*)d_in[3];
    float* out = (float*)d_out;

    bf16* xb  = (bf16*)d_ws;                        // 8192*1024
    bf16* waT = xb + (size_t)8192 * 1024;           // 3072*1024
    bf16* wpT = waT + (size_t)3072 * 1024;          // 1024*1024
    bf16* Qh  = wpT + (size_t)1024 * 1024;          // 64*2048*64
    bf16* Kh  = Qh + (size_t)64 * 2048 * 64;
    bf16* Vh  = Kh + (size_t)64 * 2048 * 64;
    bf16* Vt  = Vh + (size_t)64 * 2048 * 64;
    bf16* Yb  = Vt + (size_t)64 * 2048 * 64;
    float* tab = (float*)(Yb + (size_t)64 * 2048 * 64);  // 2*2048*32 f32
    bf16* embB = (bf16*)(tab + 2 * 2048 * 32);           // 2048*1024 bf16

    hipFuncSetAttribute((const void*)gemm256_k,
                        hipFuncAttributeMaxDynamicSharedMemorySize, 147456);
    hipFuncSetAttribute((const void*)attn_k,
                        hipFuncAttributeMaxDynamicSharedMemorySize, 81920);
    hipFuncSetAttribute((const void*)gemm_bt_k,
                        hipFuncAttributeMaxDynamicSharedMemorySize, 65536);

    prep_k<<<dim3(6400), dim3(256), 0, stream>>>(
        x, xb, w_attn, waT, w_proj, wpT, tab, val_embed, embB);
    gemm256_k<<<dim3((8192 / 256) * (3072 / 192)), dim3(512), 147456, stream>>>(
        xb, waT, Qh, Kh, Vh, 8192, 3072, 1024);
    rope_rms_k<<<dim3(TT / 64, BB * HH), dim3(256), 0, stream>>>(
        Qh, Kh, Vh, Vt, embB, tab);
    attn_k<<<dim3(8, BB * HH), dim3(512), 81920, stream>>>(Qh, Kh, Vt, Yb);
    gemm_bt_k<<<dim3(512), dim3(256), 65536, stream>>>(
        Yb, wpT, out, 8192, 1024, 1024);
}

// Round 24
// 166.938 us; speedup vs baseline: 1.0085x; 1.0085x over previous
//
#include <hip/hip_runtime.h>
#include <float.h>
#include <math.h>

#define BB 4
#define TT 2048
#define CC 1024
#define HH 16
#define HD 64
#define C3 3072

typedef __bf16 bf16;
typedef __bf16 bf16x8 __attribute__((ext_vector_type(8)));
typedef __bf16 bf16x4 __attribute__((ext_vector_type(4)));
typedef float f32x4 __attribute__((ext_vector_type(4)));
typedef float f32x16 __attribute__((ext_vector_type(16)));
typedef unsigned int uint32x4 __attribute__((ext_vector_type(4)));

// 0.125 * log2(e): folds the 1/sqrt(hd) scale and the exp->exp2 base change
// into Q, so softmax runs in the log2 domain (v_exp_f32 is native exp2).
#define QSCALE 0.18033688f

__device__ __forceinline__ void gload16(const void* g, void* l) {
    __builtin_amdgcn_global_load_lds(
        (const __attribute__((address_space(1))) void*)g,
        (__attribute__((address_space(3))) void*)l, 16, 0, 0);
}

// ---------------- fused prep: cvt x->bf16 | transW wa | transW wp | table
// One dispatch, block-range partitioned (branch is block-uniform).
__global__ __launch_bounds__(256) void prep_k(const float* __restrict__ x,
                                              bf16* __restrict__ xb,
                                              const float* __restrict__ wa,
                                              bf16* __restrict__ waT,
                                              const float* __restrict__ wp,
                                              bf16* __restrict__ wpT,
                                              float* __restrict__ tab) {
    const int blk = (int)blockIdx.x;
    const int tid = threadIdx.x;
    __shared__ bf16 tile[64][72];

    if (blk < 4096) {                       // ---- cvt: 4096*256 = n8 exactly
        int i = blk * 256 + tid;
        const float4* p = (const float4*)(x + (size_t)i * 8);
        float4 a = p[0], b = p[1];
        bf16x8 o;
        o[0] = (bf16)a.x; o[1] = (bf16)a.y; o[2] = (bf16)a.z; o[3] = (bf16)a.w;
        o[4] = (bf16)b.x; o[5] = (bf16)b.y; o[6] = (bf16)b.z; o[7] = (bf16)b.w;
        *(bf16x8*)(xb + (size_t)i * 8) = o;
        return;
    }
    if (blk < 5120) {                       // ---- transW (wa: 768, wp: 256)
        const float* in;
        bf16* out;
        int K = 1024, N, bx, by;
        if (blk < 4864) {
            int r = blk - 4096;
            in = wa; out = waT; N = 3072;
            bx = r % 48; by = r / 48;
        } else {
            int r = blk - 4864;
            in = wp; out = wpT; N = 1024;
            bx = r & 15; by = r >> 4;
        }
        int n0 = bx * 64, k0 = by * 64;
        int r = tid >> 2, c4 = (tid & 3) * 16;
        const float4* src = (const float4*)(in + (size_t)(k0 + r) * N + n0 + c4);
        #pragma unroll
        for (int j = 0; j < 4; ++j) {
            float4 v = src[j];
            tile[r][c4 + 4 * j + 0] = (bf16)v.x; tile[r][c4 + 4 * j + 1] = (bf16)v.y;
            tile[r][c4 + 4 * j + 2] = (bf16)v.z; tile[r][c4 + 4 * j + 3] = (bf16)v.w;
        }
        __syncthreads();
        bf16x8 o0, o1;
        #pragma unroll
        for (int j = 0; j < 8; ++j) o0[j] = tile[c4 + j][r];
        #pragma unroll
        for (int j = 0; j < 8; ++j) o1[j] = tile[c4 + 8 + j][r];
        *(bf16x8*)(out + (size_t)(n0 + r) * K + k0 + c4) = o0;
        *(bf16x8*)(out + (size_t)(n0 + r) * K + k0 + c4 + 8) = o1;
        return;
    }
    {                                       // ---- rope table: 256*256 = TT*32
        int idx = (blk - 5120) * 256 + tid;
        int t = idx >> 5;
        int j = idx & 31;
        float freq = powf(10000.0f, -((float)(2 * j)) / 64.0f);
        float ang = (float)t * freq;
        tab[idx] = cosf(ang);
        tab[TT * 32 + idx] = sinf(ang);
    }
}

// ---------------------- qkv GEMM: 256x192 tile, BK=64, 8 waves (2M x 4N,
// per-wave 128x48). Counted-vmcnt pipeline via operand split: A 3-buffered
// (prefetch distance 2), B 2-buffered (distance 1). Per iter issue B(kt+1)
// THEN A(kt+2); publish with vmcnt(4) — A(kt+2)'s 4 wave-loads stay in
// flight ACROSS the barrier (T4). LDS 144 KiB. Grid 512 = 2 balanced rounds.
__global__ __launch_bounds__(512, 1) void gemm256_k(const bf16* __restrict__ A,
                                                    const bf16* __restrict__ BT,
                                                    bf16* __restrict__ Qh,
                                                    bf16* __restrict__ Kh,
                                                    bf16* __restrict__ Vh,
                                                    int M, int N, int K) {
    extern __shared__ bf16 smem[];   // A: 3 x 16384 | B(+49152): 2 x 12288
    const int tid = threadIdx.x;
    const int w = tid >> 6, lane = tid & 63;
    const int wm = w >> 2, wn = w & 3;          // per-wave 128 x 48
    const int nwg = (int)gridDim.x;             // 512
    const int cpx = nwg >> 3;
    const int flat = (int)blockIdx.x;
    const int wg = (flat & 7) * cpx + (flat >> 3);
    const int gx = N / 192;                     // 16
    const int n0 = (wg % gx) * 192;
    const int m0 = (wg / gx) * 256;

    const int srow = lane >> 3;
    const int schunk = (lane & 7) ^ srow;
    const int xorL = (lane & 7) << 3;
    const int KT = K >> 6;                      // 16

    f32x4 acc[8][3];
    #pragma unroll
    for (int i = 0; i < 8; ++i)
        #pragma unroll
        for (int j = 0; j < 3; ++j) acc[i][j] = {0.f, 0.f, 0.f, 0.f};

    auto stageA = [&](int kt) {                 // 4 wave-loads
        bf16* Abuf = smem + (kt % 3) * 16384;
        const int k0 = kt * 64;
        #pragma unroll
        for (int ri = 0; ri < 4; ++ri) {
            int row = ri * 64 + w * 8;
            gload16(A + (size_t)(m0 + row + srow) * K + k0 + schunk * 8,
                    Abuf + row * 64);
        }
    };
    auto stageB = [&](int kt) {                 // 3 wave-loads
        bf16* Bbuf = smem + 49152 + (kt & 1) * 12288;
        const int k0 = kt * 64;
        #pragma unroll
        for (int ri = 0; ri < 3; ++ri) {
            int row = ri * 64 + w * 8;
            gload16(BT + (size_t)(n0 + row + srow) * K + k0 + schunk * 8,
                    Bbuf + row * 64);
        }
    };

    // prologue: A(0), B(0), A(1) -> vmcnt(4) keeps A(1) in flight
    stageA(0);
    stageB(0);
    stageA(1);
    asm volatile("s_waitcnt vmcnt(4)" ::: "memory");
    __builtin_amdgcn_s_barrier();
    __builtin_amdgcn_sched_barrier(0);

    for (int kt = 0; kt < KT; ++kt) {
        if (kt + 1 < KT) stageB(kt + 1);   // issue B first (retired this barrier)
        if (kt + 2 < KT) stageA(kt + 2);   // A rides across the barrier
        const bf16* Al = smem + (kt % 3) * 16384;
        const bf16* Bl = smem + 49152 + (kt & 1) * 12288;
        #pragma unroll
        for (int kh = 0; kh < 2; ++kh) {
            const int off = (kh * 32 + (lane >> 4) * 8) ^ xorL;
            bf16x8 aF[8], bF[3];
            #pragma unroll
            for (int i = 0; i < 8; ++i)
                aF[i] = *(const bf16x8*)&Al[(wm * 128 + i * 16 + (lane & 15)) * 64 + off];
            #pragma unroll
            for (int j = 0; j < 3; ++j)
                bF[j] = *(const bf16x8*)&Bl[(wn * 48 + j * 16 + (lane & 15)) * 64 + off];
            __builtin_amdgcn_s_setprio(1);
            #pragma unroll
            for (int i = 0; i < 8; ++i)
                #pragma unroll
                for (int j = 0; j < 3; ++j)
                    acc[i][j] = __builtin_amdgcn_mfma_f32_16x16x32_bf16(
                        aF[i], bF[j], acc[i][j], 0, 0, 0);
            __builtin_amdgcn_s_setprio(0);
        }
        if (kt + 1 < KT) {
            if (kt + 2 < KT) {
                asm volatile("s_waitcnt vmcnt(4)" ::: "memory");
            } else {
                asm volatile("s_waitcnt vmcnt(0)" ::: "memory");
            }
            __builtin_amdgcn_s_barrier();
            __builtin_amdgcn_sched_barrier(0);
        }
    }

    // scatter epilogue: per 16-col group (192-wide tiles straddle Q/K/V
    // boundaries; 1024 is 16-aligned so each group maps to one region+head)
    const int ncb = n0 + wn * 48;
    #pragma unroll
    for (int j = 0; j < 3; ++j) {
        const int ncbj = ncb + j * 16;
        const int region = ncbj >> 10;
        const int hj = (ncbj & 1023) >> 6;
        const int cj = (ncbj & 63) + (lane & 15);
        bf16* dst = (region == 0) ? Qh : ((region == 1) ? Kh : Vh);
        #pragma unroll
        for (int i = 0; i < 8; ++i)
            #pragma unroll
            for (int r = 0; r < 4; ++r) {
                int m = m0 + wm * 128 + i * 16 + 4 * (lane >> 4) + r;
                int b = m >> 11, t = m & (TT - 1);
                dst[((size_t)(b * HH + hj) * TT + t) * HD + cj] = (bf16)acc[i][j][r];
            }
    }
}

// ------------------------------------------------------- proj GEMM (BT)
// 128x128 tile, 4 waves; issue-early double-buffer (64 KiB LDS -> 2
// blocks/CU, grid 512 = one full co-resident round). XCD region map:
// 8 regions of 8 m-tiles x all 8 n-tiles, n-fast (B set L2-resident).
__global__ __launch_bounds__(256) void gemm_bt_k(const bf16* __restrict__ A,
                                                 const bf16* __restrict__ BT,
                                                 float* __restrict__ C,
                                                 int M, int N, int K) {
    extern __shared__ bf16 psm[];   // [2][A 128*64 | B 128*64] = 64 KiB
    const int tid = threadIdx.x;
    const int w = tid >> 6, lane = tid & 63;
    const int flat = (int)blockIdx.x;           // 0..511 (64m x 8n)
    const int xcd = flat & 7;
    const int local = flat >> 3;                // 0..63
    const int lr = local >> 3, lc = local & 7;  // n-fast
    const int m0 = (xcd * 8 + lr) * 128;
    const int n0 = lc * 128;
    const int wrow = (w >> 1) * 64, wcol = (w & 1) * 64;
    const int srow = lane >> 3;
    const int schunk = (lane & 7) ^ srow;
    const int xorL = (lane & 7) << 3;
    const int KT = K >> 6;                      // 16

    const f32x4 fz = {0.f, 0.f, 0.f, 0.f};
    f32x4 acc[4][4];
    #pragma unroll
    for (int i = 0; i < 4; ++i)
        #pragma unroll
        for (int j = 0; j < 4; ++j) acc[i][j] = fz;

    // stage one K-tile: A 128 rows + B 128 rows = 256 rows, 8 rounds x 32
    auto stage = [&](int kt, bf16* buf) {
        const int k0 = kt * 64;
        #pragma unroll
        for (int ri = 0; ri < 8; ++ri) {
            int row = ri * 32 + w * 8;
            if (row < 128) {
                gload16(A + (size_t)(m0 + row + srow) * K + k0 + schunk * 8,
                        buf + row * 64);
            } else {
                int rb = row - 128;
                gload16(BT + (size_t)(n0 + rb + srow) * K + k0 + schunk * 8,
                        buf + 8192 + rb * 64);
            }
        }
    };

    stage(0, psm);
    __syncthreads();

    for (int kt = 0; kt < KT; ++kt) {
        const int buf = kt & 1;
        if (kt + 1 < KT) stage(kt + 1, psm + (buf ^ 1) * 16384);  // issue-early
        const bf16* Al = psm + buf * 16384;
        const bf16* Bl = Al + 8192;
        #pragma unroll
        for (int kh = 0; kh < 2; ++kh) {
            const int off = (kh * 32 + (lane >> 4) * 8) ^ xorL;
            bf16x8 aF[4], bF[4];
            #pragma unroll
            for (int i = 0; i < 4; ++i) {
                aF[i] = *(const bf16x8*)&Al[(wrow + i * 16 + (lane & 15)) * 64 + off];
                bF[i] = *(const bf16x8*)&Bl[(wcol + i * 16 + (lane & 15)) * 64 + off];
            }
            __builtin_amdgcn_s_setprio(1);
            #pragma unroll
            for (int i = 0; i < 4; ++i)
                #pragma unroll
                for (int j = 0; j < 4; ++j)
                    acc[i][j] = __builtin_amdgcn_mfma_f32_16x16x32_bf16(
                        aF[i], bF[j], acc[i][j], 0, 0, 0);
            __builtin_amdgcn_s_setprio(0);
        }
        __syncthreads();   // publish: drains stage(kt+1), guards buf reuse
    }

    #pragma unroll
    for (int i = 0; i < 4; ++i)
        #pragma unroll
        for (int r = 0; r < 4; ++r) {
            size_t rowm = (size_t)(m0 + wrow + i * 16 + 4 * (lane >> 4) + r);
            #pragma unroll
            for (int j = 0; j < 4; ++j)
                C[rowm * N + n0 + wcol + j * 16 + (lane & 15)] = acc[i][j][r];
        }
}

// --------------- RoPE + RMS on Qh/Kh (in place); V+emb -> transposed Vt.
__global__ __launch_bounds__(256) void rope_rms_k(bf16* __restrict__ Qh,
                                                  bf16* __restrict__ Kh,
                                                  const bf16* __restrict__ Vh,
                                                  bf16* __restrict__ Vt,
                                                  const float* __restrict__ emb,
                                                  const float* __restrict__ tab) {
    __shared__ bf16 tile[64][72];
    const int t0 = blockIdx.x * 64;
    const int bh = blockIdx.y;
    const int h = bh & (HH - 1);
    const int w = threadIdx.x >> 6, lane = threadIdx.x & 63;
    const int j = lane & 31;
    #pragma unroll 4
    for (int i = 0; i < 16; ++i) {
        const int tl = w * 16 + i;
        const int t = t0 + tl;
        const size_t base = ((size_t)bh * TT + t) * HD + lane;
        const float cs = tab[t * 32 + j];
        const float sn = tab[TT * 32 + t * 32 + j];
        float q = (float)Qh[base], k = (float)Kh[base], v = (float)Vh[base];
        float qp = __shfl_xor(q, 32, 64), kp = __shfl_xor(k, 32, 64);
        float rq = (lane < 32) ? q * cs - qp * sn : q * cs + qp * sn;
        float rk = (lane < 32) ? k * cs - kp * sn : k * cs + kp * sn;
        float sq = rq * rq, sk = rk * rk;
        #pragma unroll
        for (int off = 1; off < 64; off <<= 1) {
            sq += __shfl_xor(sq, off, 64);
            sk += __shfl_xor(sk, off, 64);
        }
        rq *= rsqrtf(sq * (1.0f / 64.0f) + 1.1920929e-07f);
        rk *= rsqrtf(sk * (1.0f / 64.0f) + 1.1920929e-07f);
        Qh[base] = (bf16)(rq * QSCALE);
        Kh[base] = (bf16)rk;
        tile[tl][lane] = (bf16)(v + emb[(size_t)t * CC + h * HD + lane]);
    }
    __syncthreads();
    const int tt = threadIdx.x;
    const int r = tt >> 2, c4 = (tt & 3) * 16;
    bf16x8 o0, o1;
    #pragma unroll
    for (int jj = 0; jj < 8; ++jj) o0[jj] = tile[c4 + jj][r];
    #pragma unroll
    for (int jj = 0; jj < 8; ++jj) o1[jj] = tile[c4 + 8 + jj][r];
    bf16* out = Vt + (size_t)bh * HD * TT;
    *(bf16x8*)(out + (size_t)r * TT + t0 + c4) = o0;
    *(bf16x8*)(out + (size_t)r * TT + t0 + c4 + 8) = o1;
}

// ------------------------------------------------ MFMA flash attn (causal)
// 8 waves x 32 q-rows = 256 q rows/block, grid flat=512 blocks (2/CU).
// KVBLK=128, counted-vmcnt operand split: K 3-buffered (distance 2),
// V 2-buffered (distance 1). Per iter issue V(kt+1) THEN K(kt+2); publish
// with vmcnt(2) so K(kt+2) rides across the barrier. LDS 80 KiB.
// Swapped QK^T (S^T = K*Q^T, 32x32x16) -> in-register log2-domain softmax
// with defer-max; PV swapped (Y^T = V^T * P^T).
__global__ __launch_bounds__(512) void attn_k(const bf16* __restrict__ Qh,
                                              const bf16* __restrict__ Kh,
                                              const bf16* __restrict__ Vt,
                                              bf16* __restrict__ Y) {
    extern __shared__ bf16 asmem[];   // K: 3 x 8192 | V(+24576): 2 x 8192
    const int flat = (int)blockIdx.y * 8 + (int)blockIdx.x;   // 0..511
    const int slot = flat >> 3;
    const int bh = (flat & 7) * 8 + (slot & 7);   // fixes XCD per bh
    const int u = slot >> 3;                      // 0..7
    const int qb = (u < 4) ? (7 - u) : (u - 4);   // balanced CU pairs
    const int b = bh >> 4, h = bh & 15;
    const int tid = threadIdx.x, w = tid >> 6, lane = tid & 63;
    const int hi = lane >> 5, q31 = lane & 31;
    const int wq0 = qb * 256 + w * 32;
    const int qg = wq0 + q31;
    const int xr = q31 & 7;

    const bf16* Kbase = Kh + (size_t)bh * TT * HD;
    const bf16* Vbase = Vt + (size_t)bh * HD * TT;

    // Q B-operand fragments: lane holds Q[qg][ds*16 + hi*8 + 0..7]
    bf16x8 qF[4];
    {
        const bf16* qp = Qh + (size_t)bh * TT * HD + (size_t)qg * HD + hi * 8;
        #pragma unroll
        for (int ds = 0; ds < 4; ++ds) qF[ds] = *(const bf16x8*)(qp + ds * 16);
    }

    f32x16 accY[2];
    #pragma unroll
    for (int i = 0; i < 16; ++i) { accY[0][i] = 0.f; accY[1][i] = 0.f; }
    float mR = -INFINITY, lR = 0.f;

    const int srow = lane >> 3;                 // K staging: row-in-8
    const int schunk = (lane & 7) ^ srow;       // K pre-swizzled chunk
    const int vsr = lane >> 4;                  // V staging: row-in-4
    const int ktN = 2 * qb + 2;                 // 128-k tiles (>= 2)

    auto stageK = [&](int kt) {                 // 2 wave-loads
        bf16* dst = asmem + (kt % 3) * 8192;
        const int kc0 = kt * 128;
        #pragma unroll
        for (int jj = 0; jj < 2; ++jj) {
            int lr = w * 16 + jj * 8;
            gload16(Kbase + (size_t)(kc0 + lr + srow) * HD + schunk * 8,
                    dst + lr * 64);
        }
    };
    auto stageV = [&](int kt) {                 // 2 wave-loads
        bf16* dst = asmem + 24576 + (kt & 1) * 8192;
        const int kc0 = kt * 128;
        #pragma unroll
        for (int jj = 0; jj < 2; ++jj) {
            int vr = w * 8 + jj * 4;
            int vrow = vr + vsr;
            gload16(Vbase + (size_t)vrow * TT + kc0 + (((lane & 15) ^ (vrow & 7)) * 8),
                    dst + vr * 128);
        }
    };

    // prologue: K(0), V(0), K(1) -> vmcnt(2) keeps K(1) in flight (ktN>=2)
    stageK(0);
    stageV(0);
    stageK(1);
    asm volatile("s_waitcnt vmcnt(2)" ::: "memory");
    __builtin_amdgcn_s_barrier();
    __builtin_amdgcn_sched_barrier(0);

    for (int kt = 0; kt < ktN; ++kt) {
        if (kt + 1 < ktN) stageV(kt + 1);   // issue V first (retired this barrier)
        if (kt + 2 < ktN) stageK(kt + 2);   // K rides across the barrier
        const bf16* KL = asmem + (kt % 3) * 8192;
        const bf16* VL = asmem + 24576 + (kt & 1) * 8192;
        #pragma unroll
        for (int s = 0; s < 2; ++s) {
            if (kt * 128 + s * 64 > wq0 + 31) break;   // beyond causal frontier
            // ---- S^T = K @ Q^T : rows k (32 per frag), cols q ----
            f32x16 sa[2];
            #pragma unroll
            for (int i = 0; i < 16; ++i) { sa[0][i] = 0.f; sa[1][i] = 0.f; }
            __builtin_amdgcn_s_setprio(1);
            #pragma unroll
            for (int ds = 0; ds < 4; ++ds) {
                int cc = ds * 2 + hi;
                bf16x8 k0 = *(const bf16x8*)&KL[(s * 64 + q31) * 64 + ((cc ^ xr) * 8)];
                bf16x8 k1 = *(const bf16x8*)&KL[(s * 64 + 32 + q31) * 64 + ((cc ^ xr) * 8)];
                sa[0] = __builtin_amdgcn_mfma_f32_32x32x16_bf16(k0, qF[ds], sa[0], 0, 0, 0);
                sa[1] = __builtin_amdgcn_mfma_f32_32x32x16_bf16(k1, qF[ds], sa[1], 0, 0, 0);
            }
            __builtin_amdgcn_s_setprio(0);
            // ---- causal mask (only near-diagonal sub-tiles) ----
            if (kt * 128 + s * 64 + 63 > wq0) {
                #pragma unroll
                for (int kb = 0; kb < 2; ++kb)
                    #pragma unroll
                    for (int r = 0; r < 16; ++r) {
                        int k = kt * 128 + s * 64 + kb * 32 + (r & 3) + 8 * (r >> 2) + 4 * hi;
                        if (k > qg) sa[kb][r] = -1e30f;
                    }
            }
            // ---- in-register online softmax (log2 domain, defer-max) ----
            float mx = -1e30f;
            #pragma unroll
            for (int r = 0; r < 16; ++r)
                mx = fmaxf(fmaxf(sa[0][r], sa[1][r]), mx);
            mx = fmaxf(mx, __shfl_xor(mx, 32, 64));
            if (!__all(mx - mR <= 12.0f)) {   // scores bounded by 11.54
                float mnew = fmaxf(mR, mx);
                float alpha = __builtin_amdgcn_exp2f(mR - mnew);
                #pragma unroll
                for (int i = 0; i < 16; ++i) { accY[0][i] *= alpha; accY[1][i] *= alpha; }
                lR *= alpha;
                mR = mnew;
            }
            float sum0 = 0.f, sum1 = 0.f;
            #pragma unroll
            for (int r = 0; r < 16; ++r) {
                float p0 = __builtin_amdgcn_exp2f(sa[0][r] - mR);
                float p1 = __builtin_amdgcn_exp2f(sa[1][r] - mR);
                sa[0][r] = p0; sa[1][r] = p1;
                sum0 += p0; sum1 += p1;
            }
            float sum = sum0 + sum1;
            sum += __shfl_xor(sum, 32, 64);
            lR += sum;
            // ---- pack P to bf16 words, exchange halves, build B-frags ----
            unsigned int wds[2][8];
            #pragma unroll
            for (int kb = 0; kb < 2; ++kb)
                #pragma unroll
                for (int jj = 0; jj < 8; ++jj) {
                    bf16x8 tmp;   // only low 2 used
                    tmp[0] = (bf16)sa[kb][2 * jj];
                    tmp[1] = (bf16)sa[kb][2 * jj + 1];
                    wds[kb][jj] = *(unsigned int*)&tmp;
                }
            bf16x8 pF[4];
            #pragma unroll
            for (int ks = 0; ks < 4; ++ks) {
                const int kb = ks >> 1, ss = ks & 1;
                unsigned int w0 = wds[kb][4 * ss + 0], w1 = wds[kb][4 * ss + 1];
                unsigned int w2 = wds[kb][4 * ss + 2], w3 = wds[kb][4 * ss + 3];
                unsigned int t0 = hi ? w0 : w2, t1 = hi ? w1 : w3;
                unsigned int r0 = (unsigned int)__shfl_xor((int)t0, 32, 64);
                unsigned int r1 = (unsigned int)__shfl_xor((int)t1, 32, 64);
                uint32x4 fw;
                fw[0] = hi ? r0 : w0; fw[1] = hi ? r1 : w1;
                fw[2] = hi ? w2 : r0; fw[3] = hi ? w3 : r1;
                pF[ks] = *(bf16x8*)&fw;
            }
            // ---- Y^T += V^T @ P^T  (V row = d, 128-col k; chunk-XOR swz) ----
            __builtin_amdgcn_s_setprio(1);
            #pragma unroll
            for (int cd = 0; cd < 2; ++cd) {
                const int rowD = cd * 32 + q31;
                #pragma unroll
                for (int ks = 0; ks < 4; ++ks) {
                    int cc = s * 8 + ks * 2 + hi;    // chunk within 128 cols
                    bf16x8 vA = *(const bf16x8*)&VL[rowD * 128 + ((cc ^ xr) * 8)];
                    accY[cd] = __builtin_amdgcn_mfma_f32_32x32x16_bf16(
                        vA, pF[ks], accY[cd], 0, 0, 0);
                }
            }
            __builtin_amdgcn_s_setprio(0);
        }
        if (kt + 1 < ktN) {
            if (kt + 2 < ktN) {
                asm volatile("s_waitcnt vmcnt(2)" ::: "memory");
            } else {
                asm volatile("s_waitcnt vmcnt(0)" ::: "memory");
            }
            __builtin_amdgcn_s_barrier();
            __builtin_amdgcn_sched_barrier(0);
        }
    }

    // epilogue: Y[qg][h*64 + d] = accY/l ; d = cd*32 + 8g + 4hi + 0..3
    float inv = 1.0f / lR;
    bf16* yp = Y + ((size_t)(b * TT + qg)) * CC + h * HD;
    #pragma unroll
    for (int cd = 0; cd < 2; ++cd)
        #pragma unroll
        for (int g = 0; g < 4; ++g) {
            int d0 = cd * 32 + 8 * g + 4 * hi;
            bf16x4 o;
            o[0] = (bf16)(accY[cd][4 * g + 0] * inv);
            o[1] = (bf16)(accY[cd][4 * g + 1] * inv);
            o[2] = (bf16)(accY[cd][4 * g + 2] * inv);
            o[3] = (bf16)(accY[cd][4 * g + 3] * inv);
            *(bf16x4*)(yp + d0) = o;
        }
}

extern "C" void kernel_launch(void* const* d_in, const int* in_sizes, int n_in,
                              void* d_out, int out_size, void* d_ws, size_t ws_size,
                              hipStream_t stream) {
    const float* x         = (const float*)d_in[0];
    const float* w_attn    = (const float*)d_in[1];
    const float* w_proj    = (const float*)d_in[2];
    const float* val_embed = (const float*)d_in[3];
    float* out = (float*)d_out;

    bf16* xb  = (bf16*)d_ws;                        // 8192*1024
    bf16* waT = xb + (size_t)8192 * 1024;           // 3072*1024
    bf16* wpT = waT + (size_t)3072 * 1024;          // 1024*1024
    bf16* Qh  = wpT + (size_t)1024 * 1024;          // 64*2048*64
    bf16* Kh  = Qh + (size_t)64 * 2048 * 64;
    bf16* Vh  = Kh + (size_t)64 * 2048 * 64;
    bf16* Vt  = Vh + (size_t)64 * 2048 * 64;
    bf16* Yb  = Vt + (size_t)64 * 2048 * 64;
    float* tab = (float*)(Yb + (size_t)64 * 2048 * 64);  // 2*2048*32 f32

    hipFuncSetAttribute((const void*)gemm256_k,
                        hipFuncAttributeMaxDynamicSharedMemorySize, 147456);
    hipFuncSetAttribute((const void*)attn_k,
                        hipFuncAttributeMaxDynamicSharedMemorySize, 81920);
    hipFuncSetAttribute((const void*)gemm_bt_k,
                        hipFuncAttributeMaxDynamicSharedMemorySize, 65536);

    prep_k<<<dim3(5376), dim3(256), 0, stream>>>(
        x, xb, w_attn, waT, w_proj, wpT, tab);
    gemm256_k<<<dim3((8192 / 256) * (3072 / 192)), dim3(512), 147456, stream>>>(
        xb, waT, Qh, Kh, Vh, 8192, 3072, 1024);
    rope_rms_k<<<dim3(TT / 64, BB * HH), dim3(256), 0, stream>>>(
        Qh, Kh, Vh, Vt, val_embed, tab);
    attn_k<<<dim3(8, BB * HH), dim3(512), 81920, stream>>>(Qh, Kh, Vt, Yb);
    gemm_bt_k<<<dim3(512), dim3(256), 65536, stream>>>(
        Yb, wpT, out, 8192, 1024, 1024);
}